// Round 11
// baseline (306.480 us; speedup 1.0000x reference)
//
#include <hip/hip_runtime.h>

typedef unsigned short u16;
typedef unsigned int   u32;
typedef __bf16 v8bf __attribute__((ext_vector_type(8)));
typedef float  v4f  __attribute__((ext_vector_type(4)));

#define INV_SQRT_W   0.044194173824159216f   // 1/sqrt(512)
#define INV_SQRT_KKC 0.029462782549439483f   // 1/sqrt(3*3*128)
#define LRELU_GAIN   1.4142135623730951f

__device__ __forceinline__ u16 f2bf(float f) {
    u32 u = __float_as_uint(f);
    u = (u + 0x7fffu + ((u >> 16) & 1u)) >> 16;   // RNE
    return (u16)u;
}

// ---------------- kernel S: s[n,i] = z @ (aw/sqrt(512)) + ab ----------------
__global__ void k_s(const float* __restrict__ dlat,
                    const float* __restrict__ aw,
                    const float* __restrict__ ab,
                    const int*   __restrict__ lidx,
                    float* __restrict__ s_out)
{
    const int n   = blockIdx.x;      // 8
    const int tid = threadIdx.x;     // 256
    const int i   = tid & 127, kh = tid >> 7;
    const int li  = lidx[0];
    const float* z = dlat + (n * 16 + li) * 512 + kh * 256;
    const float* a = aw + kh * 256 * 128 + i;
    float a0 = 0.f, a1 = 0.f, a2 = 0.f, a3 = 0.f;
    for (int k = 0; k < 256; k += 4) {
        a0 += z[k + 0] * a[(k + 0) * 128];
        a1 += z[k + 1] * a[(k + 1) * 128];
        a2 += z[k + 2] * a[(k + 2) * 128];
        a3 += z[k + 3] * a[(k + 3) * 128];
    }
    __shared__ float part[256];
    part[tid] = a0 + a1 + a2 + a3;
    __syncthreads();
    if (tid < 128)
        s_out[n * 128 + i] = (part[i] + part[i + 128]) * INV_SQRT_W + ab[i];
}

// ---------------- kernel W2: W2[i,o] = sum_t (cw[t,i,o]*inv)^2 ----------------
__global__ void k_w2(const float* __restrict__ cw, float* __restrict__ W2)
{
    const int idx = blockIdx.x * 256 + threadIdx.x;   // 16384 = i*128+o
    float acc = 0.f;
    #pragma unroll
    for (int t = 0; t < 9; ++t) {
        float w = cw[t * 16384 + idx];
        acc += w * w;
    }
    W2[idx] = acc * (INV_SQRT_KKC * INV_SQRT_KKC);
}

// ---------------- kernel D: d[n,o] = rsqrt(sum_i W2[i,o]*s2[n,i] + 1e-8) ----------------
__global__ void k_d(const float* __restrict__ W2,
                    const float* __restrict__ s_buf,
                    float* __restrict__ d_out)
{
    const int n = blockIdx.x;   // 8
    const int o = threadIdx.x;  // 128
    __shared__ float s2[128];
    float sv = s_buf[n * 128 + o];
    s2[o] = sv * sv;
    __syncthreads();
    float acc = 1e-8f;
    #pragma unroll 4
    for (int i = 0; i < 128; ++i)
        acc += W2[i * 128 + o] * s2[i];
    d_out[n * 128 + o] = 1.0f / sqrtf(acc);
}

// -------- kernel WMOD: 36 stages of 8KB, layout [g:4][cout:128][8ci] bf16 --------
// stage s = q4*9 + tw*3 + th  (q4: 32-ci block, tap = th*3+tw).
__global__ void k_wmod(const float* __restrict__ cw,
                       const float* __restrict__ s_buf,
                       const float* __restrict__ d_buf,
                       u16* __restrict__ wmod)
{
    const int b   = blockIdx.x;          // 288 = n*36 + s
    const int n   = b / 36;
    const int s   = b - n * 36;
    const int q4  = s / 9;
    const int r   = s - q4 * 9;
    const int tw  = r / 3, th = r - tw * 3;
    const int tap = th * 3 + tw;
    const int cibase = q4 * 32;
    const int tid = threadIdx.x;         // 256
    __shared__ float ssh[32], dsh[128];
    if (tid < 32)  ssh[tid] = s_buf[n * 128 + cibase + tid] * INV_SQRT_KKC;
    if (tid < 128) dsh[tid] = d_buf[n * 128 + tid];
    __syncthreads();
    u16* wt = wmod + ((size_t)b << 12);   // 4096 u16 per stage
    #pragma unroll
    for (int rep = 0; rep < 2; ++rep) {
        int t2   = rep * 256 + tid;       // 512 (g,cout) pairs
        int g    = t2 >> 7;
        int cout = t2 & 127;
        float dv = dsh[cout];
        u32 pk[4];
        #pragma unroll
        for (int jj = 0; jj < 4; ++jj) {
            int cl = g * 8 + jj * 2;
            float v0 = cw[((tap * 128 + cibase + cl) << 7) + cout]     * ssh[cl]     * dv;
            float v1 = cw[((tap * 128 + cibase + cl + 1) << 7) + cout] * ssh[cl + 1] * dv;
            pk[jj] = (u32)f2bf(v0) | ((u32)f2bf(v1) << 16);
        }
        *(uint4*)&wt[(g << 10) + (cout << 3)] = *(uint4*)pk;
    }
}

// ---------------- kernel CONV: persistent blocks, 3-slot ci-quarter A-ring ----------------
// 768 blocks (3/CU, all co-resident), each owns 5-6 consecutive tiles (128px x 128cout).
// 4 waves (2M x 2N), acc[4][4]. A: ring of 3 quarter-halos (10x18x32ci, 11.4KB each,
// slab [g:4][q:180][8ci] stride 1456 u16). During quarter gq's 9 steps: issue next
// quarter's x loads early, commit cvt+ds_write late, ONE barrier per quarter.
// B: global->reg 2-deep prefetch (L2-resident wmod, per-XCD one image).
template<int S>
__device__ __forceinline__ void conv_step(const u16* __restrict__ bl,
                                          const u16* a_cur,
                                          v8bf af[6], v8bf bfP[2][4],
                                          v4f acc[4][4])
{
    constexpr int ST = S % 9, tw = ST / 3, th = ST % 3, par = S & 1;
    if constexpr (th == 0) {
        #pragma unroll
        for (int rr = 0; rr < 6; ++rr)
            af[rr] = *(const v8bf*)(a_cur + (rr * 18 + tw) * 8);
    }
    #pragma unroll
    for (int mi = 0; mi < 4; ++mi)
        #pragma unroll
        for (int ni = 0; ni < 4; ++ni)
            acc[mi][ni] = __builtin_amdgcn_mfma_f32_16x16x32_bf16(
                af[mi + th], bfP[par][ni], acc[mi][ni], 0, 0, 0);
    if constexpr (S + 2 < 36) {
        #pragma unroll
        for (int ni = 0; ni < 4; ++ni)
            bfP[par][ni] = *(const v8bf*)(bl + (S + 2) * 4096 + ni * 128);
    }
}

__global__ __launch_bounds__(256, 3) void k_conv(
    const float* __restrict__ x,
    const float* __restrict__ noise,
    const float* __restrict__ conv_b,
    const float* __restrict__ nstr,
    const u16*   __restrict__ wmod,
    float* __restrict__ out)
{
    __shared__ __align__(16) u16 xs[17472];   // 3 slots x 4 slabs x 1456 u16 = 34944 B

    const int r0 = blockIdx.x;                   // 768
    const int r  = ((r0 & 7) * 96) + (r0 >> 3);  // XCD-contiguous tile-range id
    const int nt = 5 + (((r % 3) == 0) ? 1 : 0); // 256 ranges of 6, 512 of 5 = 4096 tiles
    const int t0 = 5 * r + (r + 2) / 3;

    const int tid  = threadIdx.x;
    const int lane = tid & 63;
    const int wid  = tid >> 6;
    const int wm   = wid >> 1;         // M half (rows wm*4..wm*4+3)
    const int wq   = wid & 1;          // N half (couts wq*64..)
    const int lr   = lane & 15;
    const int kg   = lane >> 4;

    // per-thread staging constants: 720 items = 180 px x 4 granules, 3 per thread
    int s_q[3], s_g[3], s_rr[3], s_cc[3]; bool s_v[3];
    #pragma unroll
    for (int j = 0; j < 3; ++j) {
        int tj = tid + j * 256;
        s_v[j]  = (tj < 720);
        s_q[j]  = tj >> 2;
        s_g[j]  = tj & 3;
        s_rr[j] = s_q[j] / 18;
        s_cc[j] = s_q[j] - s_rr[j] * 18;
    }

    const int a_off = kg * 1456 + (wm * 72 + lr) * 8;
    const int b_off = kg * 1024 + (wq * 64 + lr) * 8;

    float4 sa[3], sb[3];
    const float4 f4z = {0.f, 0.f, 0.f, 0.f};

#define ISSUE(Q4, H0, W0, XB, EN)                                                  \
    {                                                                              \
        _Pragma("unroll")                                                          \
        for (int j = 0; j < 3; ++j) {                                              \
            int gh = (H0) + s_rr[j] - 1, gw = (W0) + s_cc[j] - 1;                  \
            bool ok = (EN) && s_v[j] && (unsigned)gh < 256u && (unsigned)gw < 256u;\
            const float* sp = (XB) + (ok ? (size_t)(((gh << 8) + gw) * 128         \
                                   + (Q4) * 32 + s_g[j] * 8) : (size_t)0);         \
            sa[j] = ok ? *(const float4*)sp       : f4z;                           \
            sb[j] = ok ? *(const float4*)(sp + 4) : f4z;                           \
        }                                                                          \
    }

#define COMMIT(SLOT, EN)                                                           \
    if (EN) {                                                                      \
        _Pragma("unroll")                                                          \
        for (int j = 0; j < 3; ++j) if (s_v[j]) {                                  \
            v8bf pk;                                                               \
            pk[0]=(__bf16)sa[j].x; pk[1]=(__bf16)sa[j].y;                          \
            pk[2]=(__bf16)sa[j].z; pk[3]=(__bf16)sa[j].w;                          \
            pk[4]=(__bf16)sb[j].x; pk[5]=(__bf16)sb[j].y;                          \
            pk[6]=(__bf16)sb[j].z; pk[7]=(__bf16)sb[j].w;                          \
            *(v8bf*)&xs[(SLOT) * 5824 + s_g[j] * 1456 + s_q[j] * 8] = pk;          \
        }                                                                          \
    }

#define QBAR()                                                                     \
    asm volatile("s_waitcnt lgkmcnt(0)" ::: "memory");                             \
    __builtin_amdgcn_s_barrier();                                                  \
    asm volatile("" ::: "memory");

    int slot = 0;

    // ---- block prologue (once per 5-6 tiles): stage (tile t0, q4=0) into slot 0 ----
    {
        const int tile = t0;
        const int pn  = tile >> 9;
        const int ph0 = ((tile >> 4) & 31) << 3;
        const int pw0 = (tile & 15) << 4;
        const float* pxb = x + ((size_t)pn << 16) * 128;
        ISSUE(0, ph0, pw0, pxb, true)
        COMMIT(0, true)
        QBAR()
    }

    const float ns = nstr[0];
    float cb4[4];
    #pragma unroll
    for (int ni = 0; ni < 4; ++ni)
        cb4[ni] = conv_b[wq * 64 + ni * 16 + lr];

    for (int t = 0; t < nt; ++t) {
        const int tile = t0 + t;
        const int n  = tile >> 9;
        const int h0 = ((tile >> 4) & 31) << 3;
        const int w0 = (tile & 15) << 4;
        const float* xb = x + ((size_t)n << 16) * 128;
        const u16* bl = wmod + (size_t)n * 147456 + b_off;

        const bool hn = (t + 1 < nt);          // last tile: next block stages its own q0
        const int tile2 = hn ? (tile + 1) : tile;
        const int n2  = tile2 >> 9;
        const int h02 = ((tile2 >> 4) & 31) << 3;
        const int w02 = (tile2 & 15) << 4;
        const float* xb2 = x + ((size_t)n2 << 16) * 128;

        // B prologue for this tile (steps 0,1); L2-hot after first tile
        v8bf bfP[2][4];
        #pragma unroll
        for (int p = 0; p < 2; ++p)
            #pragma unroll
            for (int ni = 0; ni < 4; ++ni)
                bfP[p][ni] = *(const v8bf*)(bl + p * 4096 + ni * 128);

        v4f acc[4][4];
        #pragma unroll
        for (int a = 0; a < 4; ++a)
            #pragma unroll
            for (int b2 = 0; b2 < 4; ++b2) {
                v4f zz = {0.f, 0.f, 0.f, 0.f};
                acc[a][b2] = zz;
            }

        v8bf af[6];
        int snxt = slot + 1; if (snxt == 3) snxt = 0;
        const u16* a_cur = &xs[slot * 5824 + a_off];

        // ---- quarter 0 (ci 0..31): stage q4=1 -> snxt ----
        ISSUE(1, h0, w0, xb, true)
        conv_step< 0>(bl, a_cur, af, bfP, acc);
        conv_step< 1>(bl, a_cur, af, bfP, acc);
        conv_step< 2>(bl, a_cur, af, bfP, acc);
        conv_step< 3>(bl, a_cur, af, bfP, acc);
        conv_step< 4>(bl, a_cur, af, bfP, acc);
        conv_step< 5>(bl, a_cur, af, bfP, acc);
        conv_step< 6>(bl, a_cur, af, bfP, acc);
        COMMIT(snxt, true)
        conv_step< 7>(bl, a_cur, af, bfP, acc);
        conv_step< 8>(bl, a_cur, af, bfP, acc);
        QBAR()
        slot = snxt; snxt = slot + 1; if (snxt == 3) snxt = 0;
        a_cur = &xs[slot * 5824 + a_off];

        // ---- quarter 1 (ci 32..63): stage q4=2 -> snxt ----
        ISSUE(2, h0, w0, xb, true)
        conv_step< 9>(bl, a_cur, af, bfP, acc);
        conv_step<10>(bl, a_cur, af, bfP, acc);
        conv_step<11>(bl, a_cur, af, bfP, acc);
        conv_step<12>(bl, a_cur, af, bfP, acc);
        conv_step<13>(bl, a_cur, af, bfP, acc);
        conv_step<14>(bl, a_cur, af, bfP, acc);
        conv_step<15>(bl, a_cur, af, bfP, acc);
        COMMIT(snxt, true)
        conv_step<16>(bl, a_cur, af, bfP, acc);
        conv_step<17>(bl, a_cur, af, bfP, acc);
        QBAR()
        slot = snxt; snxt = slot + 1; if (snxt == 3) snxt = 0;
        a_cur = &xs[slot * 5824 + a_off];

        // ---- quarter 2 (ci 64..95): stage q4=3 -> snxt ----
        ISSUE(3, h0, w0, xb, true)
        conv_step<18>(bl, a_cur, af, bfP, acc);
        conv_step<19>(bl, a_cur, af, bfP, acc);
        conv_step<20>(bl, a_cur, af, bfP, acc);
        conv_step<21>(bl, a_cur, af, bfP, acc);
        conv_step<22>(bl, a_cur, af, bfP, acc);
        conv_step<23>(bl, a_cur, af, bfP, acc);
        conv_step<24>(bl, a_cur, af, bfP, acc);
        COMMIT(snxt, true)
        conv_step<25>(bl, a_cur, af, bfP, acc);
        conv_step<26>(bl, a_cur, af, bfP, acc);
        QBAR()
        slot = snxt; snxt = slot + 1; if (snxt == 3) snxt = 0;
        a_cur = &xs[slot * 5824 + a_off];

        // ---- quarter 3 (ci 96..127): stage next tile's q4=0 -> snxt (if any) ----
        ISSUE(0, h02, w02, xb2, hn)
        conv_step<27>(bl, a_cur, af, bfP, acc);
        conv_step<28>(bl, a_cur, af, bfP, acc);
        conv_step<29>(bl, a_cur, af, bfP, acc);
        conv_step<30>(bl, a_cur, af, bfP, acc);
        conv_step<31>(bl, a_cur, af, bfP, acc);
        conv_step<32>(bl, a_cur, af, bfP, acc);
        conv_step<33>(bl, a_cur, af, bfP, acc);
        COMMIT(snxt, hn)
        conv_step<34>(bl, a_cur, af, bfP, acc);
        conv_step<35>(bl, a_cur, af, bfP, acc);
        QBAR()
        slot = snxt;

        // ---- epilogue for this tile: + noise*strength + bias, lrelu * sqrt(2) ----
        #pragma unroll
        for (int mi = 0; mi < 4; ++mi) {
            const int h = h0 + wm * 4 + mi;
            #pragma unroll
            for (int j = 0; j < 4; ++j) {
                const int w  = w0 + kg * 4 + j;
                const float nz = noise[((n << 8) + h) * 256 + w] * ns;
                float* orow = out + (size_t)((((n << 8) + h) << 8) + w) * 128;
                #pragma unroll
                for (int ni = 0; ni < 4; ++ni) {
                    const int cout = wq * 64 + ni * 16 + lr;
                    float v = acc[mi][ni][j] + nz + cb4[ni];
                    v = (v < 0.f ? 0.2f * v : v) * LRELU_GAIN;
                    orow[cout] = v;
                }
            }
        }
    }
}

extern "C" void kernel_launch(void* const* d_in, const int* in_sizes, int n_in,
                              void* d_out, int out_size, void* d_ws, size_t ws_size,
                              hipStream_t stream) {
    const float* x     = (const float*)d_in[0];
    const float* dlat  = (const float*)d_in[1];
    const float* noise = (const float*)d_in[2];
    const float* aw    = (const float*)d_in[3];
    const float* ab    = (const float*)d_in[4];
    const float* cw    = (const float*)d_in[5];
    const float* cb    = (const float*)d_in[6];
    const float* nstr  = (const float*)d_in[7];
    const int*   lidx  = (const int*)d_in[8];
    float* out = (float*)d_out;

    float* s_buf = (float*)d_ws;                               // 4KB
    float* d_buf = (float*)((char*)d_ws + 4096);               // 4KB
    float* W2    = (float*)((char*)d_ws + 8192);
    u16*   wmod  = (u16*)((char*)d_ws + 8192);                 // 2.25MB (aliases W2, ordered)

    k_w2  <<<64,  256, 0, stream>>>(cw, W2);
    k_s   <<<8,   256, 0, stream>>>(dlat, aw, ab, lidx, s_buf);
    k_d   <<<8,   128, 0, stream>>>(W2, s_buf, d_buf);
    k_wmod<<<288, 256, 0, stream>>>(cw, s_buf, d_buf, wmod);
    k_conv<<<768, 256, 0, stream>>>(x, noise, cb, nstr, wmod, out);
}

// Round 12
// 211.694 us; speedup vs baseline: 1.4478x; 1.4478x over previous
//
#include <hip/hip_runtime.h>

typedef unsigned short u16;
typedef unsigned int   u32;
typedef __bf16 v8bf __attribute__((ext_vector_type(8)));
typedef float  v4f  __attribute__((ext_vector_type(4)));

#define INV_SQRT_W   0.044194173824159216f   // 1/sqrt(512)
#define INV_SQRT_KKC 0.029462782549439483f   // 1/sqrt(3*3*128)
#define LRELU_GAIN   1.4142135623730951f

__device__ __forceinline__ u16 f2bf(float f) {
    u32 u = __float_as_uint(f);
    u = (u + 0x7fffu + ((u >> 16) & 1u)) >> 16;   // RNE
    return (u16)u;
}

__device__ __forceinline__ void glds16(const u16* g, u16* l) {
    __builtin_amdgcn_global_load_lds(
        (const __attribute__((address_space(1))) void*)g,
        (__attribute__((address_space(3))) void*)l, 16, 0, 0);
}

// ---------------- kernel S: s[n,i] = z @ (aw/sqrt(512)) + ab ----------------
__global__ void k_s(const float* __restrict__ dlat,
                    const float* __restrict__ aw,
                    const float* __restrict__ ab,
                    const int*   __restrict__ lidx,
                    float* __restrict__ s_out)
{
    const int n   = blockIdx.x;      // 8
    const int tid = threadIdx.x;     // 256
    const int i   = tid & 127, kh = tid >> 7;
    const int li  = lidx[0];
    const float* z = dlat + (n * 16 + li) * 512 + kh * 256;
    const float* a = aw + kh * 256 * 128 + i;
    float a0 = 0.f, a1 = 0.f, a2 = 0.f, a3 = 0.f;
    for (int k = 0; k < 256; k += 4) {
        a0 += z[k + 0] * a[(k + 0) * 128];
        a1 += z[k + 1] * a[(k + 1) * 128];
        a2 += z[k + 2] * a[(k + 2) * 128];
        a3 += z[k + 3] * a[(k + 3) * 128];
    }
    __shared__ float part[256];
    part[tid] = a0 + a1 + a2 + a3;
    __syncthreads();
    if (tid < 128)
        s_out[n * 128 + i] = (part[i] + part[i + 128]) * INV_SQRT_W + ab[i];
}

// ---------------- kernel W2: W2[i,o] = sum_t (cw[t,i,o]*inv)^2 ----------------
__global__ void k_w2(const float* __restrict__ cw, float* __restrict__ W2)
{
    const int idx = blockIdx.x * 256 + threadIdx.x;   // 16384 = i*128+o
    float acc = 0.f;
    #pragma unroll
    for (int t = 0; t < 9; ++t) {
        float w = cw[t * 16384 + idx];
        acc += w * w;
    }
    W2[idx] = acc * (INV_SQRT_KKC * INV_SQRT_KKC);
}

// ---------------- kernel D: d[n,o] = rsqrt(sum_i W2[i,o]*s2[n,i] + 1e-8) ----------------
__global__ void k_d(const float* __restrict__ W2,
                    const float* __restrict__ s_buf,
                    float* __restrict__ d_out)
{
    const int n = blockIdx.x;   // 8
    const int o = threadIdx.x;  // 128
    __shared__ float s2[128];
    float sv = s_buf[n * 128 + o];
    s2[o] = sv * sv;
    __syncthreads();
    float acc = 1e-8f;
    #pragma unroll 4
    for (int i = 0; i < 128; ++i)
        acc += W2[i * 128 + o] * s2[i];
    d_out[n * 128 + o] = 1.0f / sqrtf(acc);
}

// -------- kernel WMOD: 36 stages of 8KB, layout [g:4][cout:128][8ci] bf16 --------
// stage s = q4*9 + tw*3 + th  (q4: 32-ci block, tap = th*3+tw)  -> th-inner order.
__global__ void k_wmod(const float* __restrict__ cw,
                       const float* __restrict__ s_buf,
                       const float* __restrict__ d_buf,
                       u16* __restrict__ wmod)
{
    const int b   = blockIdx.x;          // 288 = n*36 + s
    const int n   = b / 36;
    const int s   = b - n * 36;
    const int q4  = s / 9;
    const int r   = s - q4 * 9;
    const int tw  = r / 3, th = r - tw * 3;
    const int tap = th * 3 + tw;
    const int cibase = q4 * 32;
    const int tid = threadIdx.x;         // 256
    __shared__ float ssh[32], dsh[128];
    if (tid < 32)  ssh[tid] = s_buf[n * 128 + cibase + tid] * INV_SQRT_KKC;
    if (tid < 128) dsh[tid] = d_buf[n * 128 + tid];
    __syncthreads();
    u16* wt = wmod + ((size_t)b << 12);   // 4096 u16 per stage
    #pragma unroll
    for (int rep = 0; rep < 2; ++rep) {
        int t2   = rep * 256 + tid;       // 512 (g,cout) pairs
        int g    = t2 >> 7;
        int cout = t2 & 127;
        float dv = dsh[cout];
        u32 pk[4];
        #pragma unroll
        for (int jj = 0; jj < 4; ++jj) {
            int cl = g * 8 + jj * 2;
            float v0 = cw[((tap * 128 + cibase + cl) << 7) + cout]     * ssh[cl]     * dv;
            float v1 = cw[((tap * 128 + cibase + cl + 1) << 7) + cout] * ssh[cl + 1] * dv;
            pk[jj] = (u32)f2bf(v0) | ((u32)f2bf(v1) << 16);
        }
        *(uint4*)&wt[(g << 10) + (cout << 3)] = *(uint4*)pk;
    }
}

// ---------------- kernel CONV: R5 structure + th-inner af[6] reuse + conflict-free staging ----
// 256 threads = 4 waves (2M x 2N); block tile 128 px (8h x 16w) x 128 cout; grid 4096.
// Wave: 64 px x 64 cout = 4 Mfrag x 4 Nfrag (acc[4][4], 64 AGPR). 36 stages (K=32),
// th-inner order: af[6] loaded once per th-triple (6 ds_reads / 48 MFMA).
// xs: ci-half halo, 8 slabs x 1448 u16 (stride 5792B: g*724 mod 32 all-distinct ->
// staging ds_writes conflict-free). wsh: glds double-buffered 8KB B stages.
// LDS 39552B -> 4 blocks/CU = 16 waves/CU.
template<int T>
__device__ __forceinline__ void conv_step(const u16* __restrict__ wn,
                                          u16* __restrict__ wsh,
                                          const u16* a_base,
                                          const u16* b_lane,
                                          v8bf af[6], v4f acc[4][4],
                                          int wid, int lane)
{
    constexpr int q4 = T / 9, r = T % 9, tw = r / 3, th = r % 3;
    constexpr int c  = T & 1, hq = q4 & 1;
    if constexpr (T < 35) {              // prefetch next B stage into other buffer
        #pragma unroll
        for (int t = 0; t < 2; ++t) {
            int chunk = wid + (t << 2);
            glds16(wn + (T + 1) * 4096 + (chunk << 9) + (lane << 3),
                   &wsh[((c ^ 1) << 12) + (chunk << 9) + (lane << 3)]);
        }
    }
    if constexpr (th == 0) {
        #pragma unroll
        for (int j = 0; j < 6; ++j)
            af[j] = *(const v8bf*)(a_base + hq * 5792 + (j * 18 + tw) * 8);
    }
    v8bf bf[4];
    #pragma unroll
    for (int ni = 0; ni < 4; ++ni)
        bf[ni] = *(const v8bf*)(b_lane + (c << 12) + (ni << 7));
    #pragma unroll
    for (int mi = 0; mi < 4; ++mi)
        #pragma unroll
        for (int ni = 0; ni < 4; ++ni)
            acc[mi][ni] = __builtin_amdgcn_mfma_f32_16x16x32_bf16(
                af[mi + th], bf[ni], acc[mi][ni], 0, 0, 0);
    __syncthreads();   // done with wsh[c]; wsh[c^1] glds drained at barrier
}

__global__ __launch_bounds__(256, 4) void k_conv(
    const float* __restrict__ x,
    const float* __restrict__ noise,
    const float* __restrict__ conv_b,
    const float* __restrict__ nstr,
    const u16*   __restrict__ wmod,
    float* __restrict__ out)
{
    __shared__ __align__(16) u16 xs[11584];       // 8 slabs x 1448 u16 (ci-half halo)
    __shared__ __align__(16) u16 wsh[8192];       // 2 x 8KB B stages (glds dest)

    const int bid0 = blockIdx.x;
    const int bid  = ((bid0 & 7) << 9) + (bid0 >> 3);   // XCD swizzle (4096%8==0, bijective)
    const int n   = bid >> 9;
    const int hb  = (bid >> 4) & 31;
    const int wb  = bid & 15;
    const int h0  = hb << 3, w0 = wb << 4;

    const int tid  = threadIdx.x;
    const int lane = tid & 63;
    const int wid  = tid >> 6;
    const int wm   = wid >> 1;         // M half (rows wm*4..wm*4+3)
    const int wq   = wid & 1;          // N half (couts wq*64..)
    const int lr   = lane & 15;
    const int kg   = lane >> 4;

    const float* xbase = x + ((size_t)n << 16) * 128;

    // ---- stage X halo half (10 x 18 x 64ci) fp32 -> bf16 ----
    // item i: q = i>>3 (pixel), g = i&7 (8ci granule). 8 consecutive threads share q
    // (128B contiguous global read); slab stride 1448 u16 -> ds_write conflict-free.
    #define STAGE_X(ph)                                                              \
    for (int t = tid; t < 1440; t += 256) {                                          \
        int q = t >> 3, g = t & 7;                                                   \
        int rr_ = q / 18, cc = q - rr_ * 18;                                         \
        int gh = h0 + rr_ - 1, gw = w0 + cc - 1;                                     \
        float v0=0.f,v1=0.f,v2=0.f,v3=0.f,v4=0.f,v5=0.f,v6=0.f,v7=0.f;               \
        if ((unsigned)gh < 256u && (unsigned)gw < 256u) {                            \
            const float* src = xbase + (size_t)((gh << 8) + gw) * 128                \
                               + (ph) * 64 + (g << 3);                               \
            float4 fa = *(const float4*)(src);                                       \
            float4 fb = *(const float4*)(src + 4);                                   \
            v0=fa.x; v1=fa.y; v2=fa.z; v3=fa.w; v4=fb.x; v5=fb.y; v6=fb.z; v7=fb.w;  \
        }                                                                            \
        v8bf pk;                                                                     \
        pk[0]=(__bf16)v0; pk[1]=(__bf16)v1; pk[2]=(__bf16)v2; pk[3]=(__bf16)v3;      \
        pk[4]=(__bf16)v4; pk[5]=(__bf16)v5; pk[6]=(__bf16)v6; pk[7]=(__bf16)v7;      \
        *(v8bf*)&xs[g * 1448 + q * 8] = pk;                                          \
    }

    STAGE_X(0)

    // ---- prologue: async-stage B stage 0 into buffer 0 ----
    const u16* wn = wmod + ((size_t)n * 36) * 4096;
    #pragma unroll
    for (int t = 0; t < 2; ++t) {
        int chunk = wid + (t << 2);
        glds16(wn + (chunk << 9) + (lane << 3), &wsh[(chunk << 9) + (lane << 3)]);
    }

    v4f acc[4][4];
    #pragma unroll
    for (int a = 0; a < 4; ++a)
        #pragma unroll
        for (int b2 = 0; b2 < 4; ++b2) {
            v4f zz = {0.f, 0.f, 0.f, 0.f};
            acc[a][b2] = zz;
        }

    // per-lane bases: A slab = kg granule, rows wm*4.., col lr; B = [g:kg][cout][8ci]
    const u16* const a_base = &xs[kg * 1448 + (wm * 72 + lr) * 8];
    const u16* const b_lane = &wsh[kg * 1024 + (wq * 64 + lr) * 8];

    __syncthreads();   // xs(half 0) + wsh buf0 ready

    v8bf af[6];
    conv_step< 0>(wn, wsh, a_base, b_lane, af, acc, wid, lane);
    conv_step< 1>(wn, wsh, a_base, b_lane, af, acc, wid, lane);
    conv_step< 2>(wn, wsh, a_base, b_lane, af, acc, wid, lane);
    conv_step< 3>(wn, wsh, a_base, b_lane, af, acc, wid, lane);
    conv_step< 4>(wn, wsh, a_base, b_lane, af, acc, wid, lane);
    conv_step< 5>(wn, wsh, a_base, b_lane, af, acc, wid, lane);
    conv_step< 6>(wn, wsh, a_base, b_lane, af, acc, wid, lane);
    conv_step< 7>(wn, wsh, a_base, b_lane, af, acc, wid, lane);
    conv_step< 8>(wn, wsh, a_base, b_lane, af, acc, wid, lane);
    conv_step< 9>(wn, wsh, a_base, b_lane, af, acc, wid, lane);
    conv_step<10>(wn, wsh, a_base, b_lane, af, acc, wid, lane);
    conv_step<11>(wn, wsh, a_base, b_lane, af, acc, wid, lane);
    conv_step<12>(wn, wsh, a_base, b_lane, af, acc, wid, lane);
    conv_step<13>(wn, wsh, a_base, b_lane, af, acc, wid, lane);
    conv_step<14>(wn, wsh, a_base, b_lane, af, acc, wid, lane);
    conv_step<15>(wn, wsh, a_base, b_lane, af, acc, wid, lane);
    conv_step<16>(wn, wsh, a_base, b_lane, af, acc, wid, lane);
    conv_step<17>(wn, wsh, a_base, b_lane, af, acc, wid, lane);

    // switch xs to ci 64..127 (all waves passed stage-17 barrier -> xs free)
    STAGE_X(1)
    __syncthreads();

    conv_step<18>(wn, wsh, a_base, b_lane, af, acc, wid, lane);
    conv_step<19>(wn, wsh, a_base, b_lane, af, acc, wid, lane);
    conv_step<20>(wn, wsh, a_base, b_lane, af, acc, wid, lane);
    conv_step<21>(wn, wsh, a_base, b_lane, af, acc, wid, lane);
    conv_step<22>(wn, wsh, a_base, b_lane, af, acc, wid, lane);
    conv_step<23>(wn, wsh, a_base, b_lane, af, acc, wid, lane);
    conv_step<24>(wn, wsh, a_base, b_lane, af, acc, wid, lane);
    conv_step<25>(wn, wsh, a_base, b_lane, af, acc, wid, lane);
    conv_step<26>(wn, wsh, a_base, b_lane, af, acc, wid, lane);
    conv_step<27>(wn, wsh, a_base, b_lane, af, acc, wid, lane);
    conv_step<28>(wn, wsh, a_base, b_lane, af, acc, wid, lane);
    conv_step<29>(wn, wsh, a_base, b_lane, af, acc, wid, lane);
    conv_step<30>(wn, wsh, a_base, b_lane, af, acc, wid, lane);
    conv_step<31>(wn, wsh, a_base, b_lane, af, acc, wid, lane);
    conv_step<32>(wn, wsh, a_base, b_lane, af, acc, wid, lane);
    conv_step<33>(wn, wsh, a_base, b_lane, af, acc, wid, lane);
    conv_step<34>(wn, wsh, a_base, b_lane, af, acc, wid, lane);
    conv_step<35>(wn, wsh, a_base, b_lane, af, acc, wid, lane);

    // ---- epilogue: + noise*strength + bias, lrelu * sqrt(2) ----
    const float ns = nstr[0];
    float cb4[4];
    #pragma unroll
    for (int ni = 0; ni < 4; ++ni)
        cb4[ni] = conv_b[wq * 64 + ni * 16 + lr];
    #pragma unroll
    for (int mi = 0; mi < 4; ++mi) {
        const int h = h0 + wm * 4 + mi;
        #pragma unroll
        for (int j = 0; j < 4; ++j) {
            const int w  = w0 + kg * 4 + j;
            const float nz = noise[((n << 8) + h) * 256 + w] * ns;
            float* orow = out + (size_t)((((n << 8) + h) << 8) + w) * 128;
            #pragma unroll
            for (int ni = 0; ni < 4; ++ni) {
                const int cout = wq * 64 + ni * 16 + lr;
                float v = acc[mi][ni][j] + nz + cb4[ni];
                v = (v < 0.f ? 0.2f * v : v) * LRELU_GAIN;
                orow[cout] = v;
            }
        }
    }
}

extern "C" void kernel_launch(void* const* d_in, const int* in_sizes, int n_in,
                              void* d_out, int out_size, void* d_ws, size_t ws_size,
                              hipStream_t stream) {
    const float* x     = (const float*)d_in[0];
    const float* dlat  = (const float*)d_in[1];
    const float* noise = (const float*)d_in[2];
    const float* aw    = (const float*)d_in[3];
    const float* ab    = (const float*)d_in[4];
    const float* cw    = (const float*)d_in[5];
    const float* cb    = (const float*)d_in[6];
    const float* nstr  = (const float*)d_in[7];
    const int*   lidx  = (const int*)d_in[8];
    float* out = (float*)d_out;

    float* s_buf = (float*)d_ws;                               // 4KB
    float* d_buf = (float*)((char*)d_ws + 4096);               // 4KB
    float* W2    = (float*)((char*)d_ws + 8192);
    u16*   wmod  = (u16*)((char*)d_ws + 8192);                 // 2.25MB (aliases W2, ordered)

    k_w2  <<<64,  256, 0, stream>>>(cw, W2);
    k_s   <<<8,   256, 0, stream>>>(dlat, aw, ab, lidx, s_buf);
    k_d   <<<8,   128, 0, stream>>>(W2, s_buf, d_buf);
    k_wmod<<<288, 256, 0, stream>>>(cw, s_buf, d_buf, wmod);
    k_conv<<<4096,256, 0, stream>>>(x, noise, cb, nstr, wmod, out);
}